// Round 1
// baseline (173.601 us; speedup 1.0000x reference)
//
#include <hip/hip_runtime.h>

// Ordered bi-bi mechanism dydt. Species: [E, EA, EQ, EAB, A, B, P, Q].
// Two lanes per element: lane pair (2j, 2j+1) holds the two float4 halves of
// element j's y-row, so every global load/store is unit-stride float4 across
// the wave. Halves + rates exchanged via __shfl_xor(.,1).
//
// This revision: each thread processes ITERS=4 rows (grid-stride batched),
// with ALL global loads issued before any shfl/compute — 8 independent 16B
// loads in flight per thread instead of 2, to lift memory-level parallelism
// (prior best was ~1.1 TB/s, 18% of achievable HBM BW => latency/issue-bound,
// not bytes-bound). Output uses non-temporal stores so the write-only result
// doesn't evict the L3-resident inputs (192 MB working set vs 256 MB L3).

typedef float v4f __attribute__((ext_vector_type(4)));

#define ITERS 4

__global__ __launch_bounds__(256) void ode_kernel(
    const float4* __restrict__ y4,
    const float4* __restrict__ kf4,
    const float4* __restrict__ kr4,
    float4* __restrict__ out4,
    int n2)   // n2 = 2*B (total float4 rows of y)
{
    const int stride = gridDim.x * blockDim.x;            // multiple of 256
    const int t0 = blockIdx.x * blockDim.x + threadIdx.x;
    const int h = t0 & 1;   // stride is even => same for all iterations

    // even lane reads forward rates, odd lane reverse rates
    const float4* __restrict__ rp = h ? kr4 : kf4;

    int   t[ITERS];
    bool  vld[ITERS];
    float4 q[ITERS], mine[ITERS];

    // ---- phase 1: issue every global load (8 independent 16B loads) ----
    #pragma unroll
    for (int k = 0; k < ITERS; ++k) {
        t[k]   = t0 + k * stride;
        vld[k] = t[k] < n2;
        if (vld[k]) {
            q[k]    = y4[t[k]];        // unit-stride float4 across wave
            mine[k] = rp[t[k] >> 1];   // unit-stride float4 across lane pairs
        }
    }

    // ---- phase 2: exchange halves, compute, store ----
    // Note: n2 is even and stride is even, so within a wave the lane pair
    // (2j, 2j+1) is always jointly valid or jointly invalid => shfl partner
    // is active whenever this lane is active.
    #pragma unroll
    for (int k = 0; k < ITERS; ++k) {
        if (!vld[k]) continue;

        float4 qq = q[k];
        float4 p;
        p.x = __shfl_xor(qq.x, 1);
        p.y = __shfl_xor(qq.y, 1);
        p.z = __shfl_xor(qq.z, 1);
        p.w = __shfl_xor(qq.w, 1);

        float4 ya = h ? p  : qq;   // E, EA, EQ, EAB
        float4 yb = h ? qq : p;    // A, B, P, Q

        float4 mm = mine[k];
        float4 other;
        other.x = __shfl_xor(mm.x, 1);
        other.y = __shfl_xor(mm.y, 1);
        other.z = __shfl_xor(mm.z, 1);
        other.w = __shfl_xor(mm.w, 1);

        float4 f = h ? other : mm;   // kf0..kf3
        float4 r = h ? mm : other;   // kr0..kr3

        float E  = ya.x, EA = ya.y, EQ = ya.z, EAB = ya.w;
        float A  = yb.x, Bc = yb.y, P  = yb.z, Q   = yb.w;

        float v0 = f.x * E   * A  - r.x * EA;
        float v1 = f.y * EA  * Bc - r.y * EAB;
        float v2 = f.z * EAB      - r.z * EQ * P;
        float v3 = f.w * EQ       - r.w * E  * Q;

        float4 o;
        if (h == 0) {
            o.x = v3 - v0;   // dE
            o.y = v0 - v1;   // dEA
            o.z = v2 - v3;   // dEQ
            o.w = v1 - v2;   // dEAB
        } else {
            o.x = -v0;       // dA
            o.y = -v1;       // dB
            o.z =  v2;       // dP
            o.w =  v3;       // dQ
        }

        // non-temporal 16B store: write-only output, don't pollute L2/L3
        v4f ov;
        ov.x = o.x; ov.y = o.y; ov.z = o.z; ov.w = o.w;
        __builtin_nontemporal_store(ov, (v4f*)(out4 + t[k]));
    }
}

extern "C" void kernel_launch(void* const* d_in, const int* in_sizes, int n_in,
                              void* d_out, int out_size, void* d_ws, size_t ws_size,
                              hipStream_t stream) {
    // inputs: [0]=t (1,), [1]=y (B,8), [2]=forward_rates (B,4), [3]=reverse_rates (B,4)
    const float4* y4  = (const float4*)d_in[1];
    const float4* kf4 = (const float4*)d_in[2];
    const float4* kr4 = (const float4*)d_in[3];
    float4* out4 = (float4*)d_out;
    int B  = in_sizes[1] / 8;
    int n2 = 2 * B;

    int block = 256;
    int grid  = (n2 + block * ITERS - 1) / (block * ITERS);
    ode_kernel<<<grid, block, 0, stream>>>(y4, kf4, kr4, out4, n2);
}